// Round 7
// baseline (453.534 us; speedup 1.0000x reference)
//
#include <hip/hip_runtime.h>
#include <math.h>

#define TPB 256
#define SCAN_ITEMS 4
#define SCAN_BLOCK (TPB * SCAN_ITEMS)
#define TIECAP 2048
#define HIST_BLOCKS 104
#define BW 512               // bucket width in vertices (2^9)
#define BUCKET_BLOCKS 2048   // 8 blocks/CU: latency-hiding for scattered writes

// ---------------- block-wide exclusive scan helper (256 threads = 4 waves) ----
static __device__ __forceinline__ int block_scan_excl(int v, int* lds, int& total)
{
    int lane = threadIdx.x & 63;
    int wid  = threadIdx.x >> 6;
    int x = v;
#pragma unroll
    for (int off = 1; off < 64; off <<= 1) {
        int y = __shfl_up(x, off, 64);
        if (lane >= off) x += y;
    }
    if (lane == 63) lds[wid] = x;
    __syncthreads();
    int t0 = lds[0], t1 = lds[1], t2 = lds[2], t3 = lds[3];
    int wOff = (wid > 0 ? t0 : 0) + (wid > 1 ? t1 : 0) + (wid > 2 ? t2 : 0);
    total = t0 + t1 + t2 + t3;
    __syncthreads();
    return wOff + x - v;   // exclusive prefix of this thread's value
}

// ---------------- init: zero hists + state + bucket cursors ----------------
__global__ void k_init(unsigned* hist, unsigned* state, int k,
                       unsigned* cursor, int NB, int CAP)
{
    int i = threadIdx.x;
    for (int j = i; j < 1024; j += blockDim.x) hist[j] = 0u;
    if (cursor) {
        for (int j = i; j < NB; j += blockDim.x)
            cursor[j * 16] = (unsigned)(j * CAP);   // 64B-padded cursors
    }
    if (i == 0) {
        state[0] = 0u;            // prefix
        state[1] = (unsigned)k;   // kk remaining
        state[2] = 0u;            // T
        state[3] = 0u;            // tie count
        state[4] = 0u;            // nValid
    }
}

// ---------------- per-vertex dot products (wave per vertex) ----------------
__global__ void k_dots(const float* __restrict__ verts,
                       const float* __restrict__ w0, const float* __restrict__ b0,
                       const float* __restrict__ w1, const float* __restrict__ b1,
                       long long* __restrict__ iacc, long long* __restrict__ s1q, int V)
{
    int gid  = blockIdx.x * blockDim.x + threadIdx.x;
    int v    = gid >> 6;
    int lane = gid & 63;
    if (v >= V) return;
    const float2 a  = ((const float2*)(verts + (size_t)v * 128))[lane];
    const float2 wa = ((const float2*)w0)[lane];
    const float2 wb = ((const float2*)w1)[lane];
    float p0 = a.x * wa.x + a.y * wa.y;
    float p1 = a.x * wb.x + a.y * wb.y;
#pragma unroll
    for (int off = 32; off > 0; off >>= 1) {
        p0 += __shfl_down(p0, off, 64);
        p1 += __shfl_down(p1, off, 64);
    }
    if (lane == 0) {
        double s0 = (double)p0 + (double)b0[0];
        double s1 = (double)p1 + (double)b1[0];
        iacc[v] = (long long)llrint(s0 * 1099511627776.0);   // 2^40 fixed point
        s1q[v]  = (long long)llrint(s1 * 1099511627776.0);
    }
}

// ---------------- fallback edge scatter (device atomics) -------------------
__global__ void k_scatter(const int2* __restrict__ edges, const long long* __restrict__ s1q,
                          unsigned long long* __restrict__ iacc, int E)
{
    int i = blockIdx.x * blockDim.x + threadIdx.x;
    if (i >= E) return;
    int2 e = edges[i];
    atomicAdd(&iacc[e.x], (unsigned long long)s1q[e.y]);
    atomicAdd(&iacc[e.y], (unsigned long long)s1q[e.x]);
}

// ---------------- phase 1: bucket the 2E endpoint updates ------------------
// element = (s1q[src] << 9) | (dst & 511); bucket = dst >> 9.
// Per block: LDS-count per bucket, ONE global reserve atomic per bucket,
// then write elements. Determinism: final sum is commutative int64 add.
__global__ void k_bucket(const int2* __restrict__ edges, const long long* __restrict__ s1q,
                         long long* __restrict__ bdata, unsigned* __restrict__ cursor,
                         int E, int NB, int CAP)
{
    __shared__ unsigned cnt[256];
    __shared__ unsigned base[256];
    const int tilesTotal = (E + 2047) / 2048;
    cnt[threadIdx.x] = 0u;
    __syncthreads();
    // pass A: count this block's elements per bucket
    for (int tile = blockIdx.x; tile < tilesTotal; tile += gridDim.x) {
        int tbase = tile * 2048;
        for (int r = 0; r < 8; ++r) {
            int i = tbase + r * 256 + threadIdx.x;
            if (i < E) {
                int2 e = edges[i];
                atomicAdd(&cnt[e.x >> 9], 1u);
                atomicAdd(&cnt[e.y >> 9], 1u);
            }
        }
    }
    __syncthreads();
    // reserve contiguous ranges (one global atomic per bucket per block)
    if (threadIdx.x < NB) {
        unsigned c = cnt[threadIdx.x];
        base[threadIdx.x] = c ? atomicAdd(&cursor[threadIdx.x * 16], c) : 0u;
        cnt[threadIdx.x] = 0u;   // reuse as local write cursor
    }
    __syncthreads();
    // pass B: re-read edges, write packed elements
    for (int tile = blockIdx.x; tile < tilesTotal; tile += gridDim.x) {
        int tbase = tile * 2048;
        for (int r = 0; r < 8; ++r) {
            int i = tbase + r * 256 + threadIdx.x;
            if (i < E) {
                int2 e = edges[i];
                long long vx = s1q[e.x], vy = s1q[e.y];
                int b0 = e.x >> 9;
                unsigned p0 = base[b0] + atomicAdd(&cnt[b0], 1u);
                if (p0 < (unsigned)(b0 + 1) * (unsigned)CAP)
                    bdata[p0] = (vy << 9) | (long long)(e.x & 511);
                int b1 = e.y >> 9;
                unsigned p1 = base[b1] + atomicAdd(&cnt[b1], 1u);
                if (p1 < (unsigned)(b1 + 1) * (unsigned)CAP)
                    bdata[p1] = (vx << 9) | (long long)(e.y & 511);
            }
        }
    }
}

// ---------------- phase 2: per-bucket LDS segmented sum + finalize ---------
// Fused k_finalize: this block owns vertices [b*BW, b*BW+BW), so it can
// emit attnf/keys for them directly (saves a launch + an iacc re-read pass).
__global__ void k_bucket_sum(const long long* __restrict__ bdata,
                             const unsigned* __restrict__ cursor,
                             long long* __restrict__ iacc,
                             float* __restrict__ attnf, unsigned* __restrict__ keys,
                             int V, int CAP)
{
    __shared__ unsigned long long acc[BW];
    int b = blockIdx.x;
    for (int j = threadIdx.x; j < BW; j += 256) acc[j] = 0ull;
    __syncthreads();
    unsigned n = cursor[b * 16] - (unsigned)(b * CAP);
    if (n > (unsigned)CAP) n = (unsigned)CAP;
    const long long* src = bdata + (size_t)b * CAP;
    for (unsigned i = threadIdx.x; i < n; i += 256) {
        long long p = src[i];
        atomicAdd(&acc[(int)(p & 511)], (unsigned long long)(p >> 9));
    }
    __syncthreads();
    for (int j = threadIdx.x; j < BW; j += 256) {
        int v = b * BW + j;
        if (v < V) {
            long long tot = iacc[v] + (long long)acc[j];
            float a = (float)((double)tot * 9.094947017729282379150390625e-13); // 2^-40
            attnf[v] = a;
            unsigned u = __float_as_uint(a);
            keys[v] = (u & 0x80000000u) ? ~u : (u | 0x80000000u);
        }
    }
}

// ---------------- fixed point -> float attn + sortable key (fallback) ------
__global__ void k_finalize(const long long* __restrict__ iacc, float* __restrict__ attnf,
                           unsigned* __restrict__ keys, int V)
{
    int i = blockIdx.x * blockDim.x + threadIdx.x;
    if (i >= V) return;
    float a = (float)((double)iacc[i] * 9.094947017729282379150390625e-13); // 2^-40
    attnf[i] = a;
    unsigned u = __float_as_uint(a);
    keys[i] = (u & 0x80000000u) ? ~u : (u | 0x80000000u);
}

// ---------------- radix select: LDS-privatized histogram pass --------------
__global__ void k_hist(const unsigned* __restrict__ keys, int V,
                       const unsigned* __restrict__ state, int shift,
                       unsigned* __restrict__ hist)
{
    __shared__ unsigned lh[256];
    lh[threadIdx.x] = 0u;      // TPB == 256
    __syncthreads();
    unsigned pref = 0u;
    if (shift != 24) pref = state[0] >> (shift + 8);
    int stride = gridDim.x * blockDim.x;
    for (int i = blockIdx.x * blockDim.x + threadIdx.x; i < V; i += stride) {
        unsigned key = keys[i];
        bool ok = (shift == 24) || ((key >> (shift + 8)) == pref);
        if (ok) atomicAdd(&lh[(key >> shift) & 255u], 1u);
    }
    __syncthreads();
    unsigned c = lh[threadIdx.x];
    if (c) atomicAdd(&hist[threadIdx.x], c);
}

// ---------------- radix select: pick bin -----------------------------------
__global__ void k_select(const unsigned* __restrict__ hist, int shift, unsigned* __restrict__ state)
{
    if (threadIdx.x != 0 || blockIdx.x != 0) return;
    unsigned kk = state[1];
    unsigned cum = 0;
    int j = 255;
    for (; j > 0; --j) {
        unsigned c = hist[j];
        if (cum + c >= kk) break;
        cum += c;
    }
    state[0] |= ((unsigned)j) << shift;
    state[1] = kk - cum;
    if (shift == 0) state[2] = state[0];  // final threshold key T
}

// ---------------- mark key>T, collect ties ---------------------------------
__global__ void k_tie_collect(const unsigned* __restrict__ keys, int V,
                              unsigned* __restrict__ state, int* __restrict__ selFlag,
                              int* __restrict__ tieList)
{
    int i = blockIdx.x * blockDim.x + threadIdx.x;
    if (i >= V) return;
    unsigned key = keys[i];
    unsigned T   = state[2];
    selFlag[i] = key > T ? 1 : 0;
    if (key == T) {
        unsigned p = atomicAdd(&state[3], 1u);
        if (p < TIECAP) tieList[p] = i;
    }
}

// ---------------- resolve ties: smallest kk indices among == T --------------
__global__ void k_tie_resolve(const unsigned* __restrict__ state,
                              const int* __restrict__ tieList, int* __restrict__ selFlag)
{
    __shared__ int s[TIECAP];
    int n  = (int)state[3];
    if (n > TIECAP) n = TIECAP;
    int kk = (int)state[1];
    int tid = threadIdx.x;
    if (kk >= n) {
        for (int i = tid; i < n; i += blockDim.x) selFlag[tieList[i]] = 1;
        return;
    }
    for (int i = tid; i < n; i += blockDim.x) s[i] = tieList[i];
    __syncthreads();
    for (int i = tid; i < n; i += blockDim.x) {
        int v = s[i];
        int r = 0;
        for (int j = 0; j < n; ++j) r += (s[j] < v);
        if (r < kk) selFlag[v] = 1;
    }
}

// ---------------- scan over V: pass A (block totals) ------------------------
__global__ void k_scanA_V(const int* __restrict__ selFlag, int V, unsigned* __restrict__ bsums)
{
    __shared__ int lds[4];
    int base = blockIdx.x * SCAN_BLOCK + threadIdx.x * SCAN_ITEMS;
    int f0 = 0, f1 = 0, f2 = 0, f3 = 0;
    if (base + 3 < V) {
        int4 q = *(const int4*)(selFlag + base);
        f0 = q.x; f1 = q.y; f2 = q.z; f3 = q.w;
    } else {
        if (base     < V) f0 = selFlag[base];
        if (base + 1 < V) f1 = selFlag[base + 1];
        if (base + 2 < V) f2 = selFlag[base + 2];
        if (base + 3 < V) f3 = selFlag[base + 3];
    }
    int tot;
    block_scan_excl(f0 + f1 + f2 + f3, lds, tot);
    if (threadIdx.x == 0) bsums[blockIdx.x] = (unsigned)tot;
}

// ---------------- scan pass B: single block over block sums -----------------
__global__ void k_scanB(unsigned* __restrict__ sums, int nb,
                        unsigned* __restrict__ totalOut, float* __restrict__ outF)
{
    __shared__ int lds[4];
    int tid = threadIdx.x;
    int running = 0;
    for (int base = 0; base < nb; base += TPB) {
        int i = base + tid;
        int v = (i < nb) ? (int)sums[i] : 0;
        int tot;
        int ex = block_scan_excl(v, lds, tot);
        if (i < nb) sums[i] = (unsigned)(ex + running);
        running += tot;
    }
    if (tid == 0) {
        if (totalOut) *totalOut = (unsigned)running;
        if (outF)     *outF    = (float)running;
    }
}

// ---------------- scan over V: pass C (write mask / selIdx / O2) ------------
__global__ void k_scanC_V(const int* __restrict__ selFlag, int V,
                          const unsigned* __restrict__ bsums,
                          int* __restrict__ mask, int* __restrict__ selIdx,
                          const int* __restrict__ vidx_in, float* __restrict__ O2)
{
    __shared__ int lds[4];
    int base = blockIdx.x * SCAN_BLOCK + threadIdx.x * SCAN_ITEMS;
    int f[4] = {0, 0, 0, 0};
    if (base + 3 < V) {
        int4 q = *(const int4*)(selFlag + base);
        f[0] = q.x; f[1] = q.y; f[2] = q.z; f[3] = q.w;
    } else {
#pragma unroll
        for (int t = 0; t < 4; ++t)
            if (base + t < V) f[t] = selFlag[base + t];
    }
    int tot;
    int run = block_scan_excl(f[0] + f[1] + f[2] + f[3], lds, tot) + (int)bsums[blockIdx.x];
#pragma unroll
    for (int t = 0; t < 4; ++t) {
        int idx = base + t;
        if (idx < V) {
            if (f[t]) {
                mask[idx]    = run;
                selIdx[run]  = idx;
                O2[run]      = (float)vidx_in[run];  // verts_idx[:k]
                run++;
            } else {
                mask[idx] = -1;
            }
        }
    }
}

// ---------------- scan over E: pass A ---------------------------------------
__global__ void k_scanA_E(const int* __restrict__ edges, int E, const int* __restrict__ mask,
                          unsigned* __restrict__ bsums)
{
    __shared__ int lds[4];
    int base = blockIdx.x * SCAN_BLOCK + threadIdx.x * SCAN_ITEMS;
    int s = 0;
    if (base + 3 < E) {
        const int4* e4 = (const int4*)edges;
        int4 q0 = e4[(base >> 1)];
        int4 q1 = e4[(base >> 1) + 1];
        s += (mask[q0.x] >= 0 && mask[q0.y] >= 0);
        s += (mask[q0.z] >= 0 && mask[q0.w] >= 0);
        s += (mask[q1.x] >= 0 && mask[q1.y] >= 0);
        s += (mask[q1.z] >= 0 && mask[q1.w] >= 0);
    } else {
        for (int t = 0; t < 4; ++t) {
            int i = base + t;
            if (i < E) {
                int a = edges[2 * i], b = edges[2 * i + 1];
                s += (mask[a] >= 0 && mask[b] >= 0);
            }
        }
    }
    int tot;
    block_scan_excl(s, lds, tot);
    if (threadIdx.x == 0) bsums[blockIdx.x] = (unsigned)tot;
}

// ---------------- scan over E: pass C (write O1 new_edges, O3 edges_idx) ----
__global__ void k_scanC_E(const int* __restrict__ edges, int E, const int* __restrict__ mask,
                          const unsigned* __restrict__ bsums, const unsigned* __restrict__ state,
                          const int* __restrict__ eidx_in,
                          float* __restrict__ O1, float* __restrict__ O3)
{
    __shared__ int lds[4];
    int base = blockIdx.x * SCAN_BLOCK + threadIdx.x * SCAN_ITEMS;
    int fl[4] = {0, 0, 0, 0};
    int m0s[4], m1s[4];
    int s = 0;
#pragma unroll
    for (int t = 0; t < 4; ++t) {
        int i = base + t;
        if (i < E) {
            int2 e = ((const int2*)edges)[i];
            int m0 = mask[e.x], m1 = mask[e.y];
            m0s[t] = m0; m1s[t] = m1;
            fl[t] = (m0 >= 0 && m1 >= 0);
            s += fl[t];
        }
    }
    int tot;
    int run = block_scan_excl(s, lds, tot) + (int)bsums[blockIdx.x];
    int nValid = (int)state[4];
#pragma unroll
    for (int t = 0; t < 4; ++t) {
        int i = base + t;
        if (i < E) {
            long long pos = fl[t] ? (long long)run : (long long)nValid + (long long)(i - run);
            float2 val;
            if (fl[t]) { val.x = (float)m0s[t]; val.y = (float)m1s[t]; }
            else       { val.x = -1.0f;         val.y = -1.0f; }
            ((float2*)O1)[pos] = val;
            O3[pos] = fl[t] ? (float)eidx_in[i] : -1.0f;
            run += fl[t];
        }
    }
}

// ---------------- gather + tanh scale: verts_up -----------------------------
__global__ void k_verts_up(const float* __restrict__ verts, const int* __restrict__ selIdx,
                           const float* __restrict__ attnf, float* __restrict__ O0, int k)
{
    int idx = blockIdx.x * blockDim.x + threadIdx.x;
    if (idx >= k * 32) return;
    int r = idx >> 5;
    int c = idx & 31;
    int v = selIdx[r];
    float t = tanhf(attnf[v]);
    float4 x = ((const float4*)verts)[(size_t)v * 32 + c];
    x.x *= t; x.y *= t; x.z *= t; x.w *= t;
    ((float4*)O0)[(size_t)r * 32 + c] = x;
}

// ============================ host launcher ================================
extern "C" void kernel_launch(void* const* d_in, const int* in_sizes, int n_in,
                              void* d_out, int out_size, void* d_ws, size_t ws_size,
                              hipStream_t stream)
{
    const float* verts = (const float*)d_in[0];
    const int*   edges = (const int*)d_in[1];
    const int*   vidx  = (const int*)d_in[2];
    const int*   eidx  = (const int*)d_in[3];
    const float* w0w   = (const float*)d_in[4];
    const float* w0b   = (const float*)d_in[5];
    const float* w1w   = (const float*)d_in[6];
    const float* w1b   = (const float*)d_in[7];

    const int V = in_sizes[2];
    const int E = in_sizes[3];
    const int F = in_sizes[0] / V;            // 128
    const int k = (int)((double)V * 0.8);     // matches python int(nv*RATIO)

    // ---- workspace carve-up ----
    char* p = (char*)d_ws;
    auto alloc = [&](size_t bytes) -> char* {
        char* r = p;
        p += (bytes + 255) & ~(size_t)255;
        return r;
    };
    long long* iacc   = (long long*)alloc((size_t)V * 8);
    long long* s1q    = (long long*)alloc((size_t)V * 8);
    float*     attnf  = (float*)alloc((size_t)V * 4);
    unsigned*  keys   = (unsigned*)alloc((size_t)V * 4);
    int*       selFlag= (int*)alloc((size_t)V * 4);
    int*       mask   = (int*)alloc((size_t)V * 4);
    int*       selIdx = (int*)alloc((size_t)k * 4);
    int*       tieList= (int*)alloc((size_t)TIECAP * 4);
    unsigned*  hist   = (unsigned*)alloc(1024 * 4);
    unsigned*  state  = (unsigned*)alloc(64);
    const int nbV = (V + SCAN_BLOCK - 1) / SCAN_BLOCK;
    const int nbE = (E + SCAN_BLOCK - 1) / SCAN_BLOCK;
    unsigned*  bsumsV = (unsigned*)alloc((size_t)nbV * 4);
    unsigned*  bsumsE = (unsigned*)alloc((size_t)nbE * 4);

    // bucket-aggregation scratch (falls back to atomic scatter if ws too small)
    const int NB  = (V + BW - 1) / BW;
    long long avgc = (2LL * E * BW) / (V > 0 ? V : 1);
    const int CAP = (int)(avgc + avgc / 8 + 1024);   // +12.5% + 1024 slack
    unsigned*  cursor = (unsigned*)alloc(256 * 64);              // 64B-padded
    long long* bdata  = (long long*)alloc((size_t)NB * CAP * 8);
    const bool useBucket = (NB <= 256) &&
                           ((size_t)(p - (char*)d_ws) <= ws_size);

    // ---- output carve-up (all written as float values) ----
    float* out = (float*)d_out;
    float* O0 = out;                         // verts_up   k*F
    float* O1 = O0 + (size_t)k * F;          // new_edges  E*2
    float* O2 = O1 + (size_t)E * 2;          // verts_idx  k
    float* O3 = O2 + (size_t)k;              // edges_idx  E
    float* O4 = O3 + (size_t)E;              // n_edges    1

    k_init<<<1, TPB, 0, stream>>>(hist, state, k,
                                  useBucket ? cursor : nullptr, NB, CAP);

    k_dots<<<(int)(((size_t)V * 64 + TPB - 1) / TPB), TPB, 0, stream>>>(
        verts, w0w, w0b, w1w, w1b, iacc, s1q, V);

    if (useBucket) {
        k_bucket<<<BUCKET_BLOCKS, TPB, 0, stream>>>((const int2*)edges, s1q, bdata, cursor, E, NB, CAP);
        k_bucket_sum<<<NB, TPB, 0, stream>>>(bdata, cursor, iacc, attnf, keys, V, CAP);
    } else {
        k_scatter<<<(E + TPB - 1) / TPB, TPB, 0, stream>>>(
            (const int2*)edges, s1q, (unsigned long long*)iacc, E);
        k_finalize<<<(V + TPB - 1) / TPB, TPB, 0, stream>>>(iacc, attnf, keys, V);
    }

    for (int r = 0; r < 4; ++r) {
        int shift = 24 - 8 * r;
        k_hist<<<HIST_BLOCKS, TPB, 0, stream>>>(keys, V, state, shift, hist + 256 * r);
        k_select<<<1, 64, 0, stream>>>(hist + 256 * r, shift, state);
    }

    k_tie_collect<<<(V + TPB - 1) / TPB, TPB, 0, stream>>>(keys, V, state, selFlag, tieList);
    k_tie_resolve<<<1, TPB, 0, stream>>>(state, tieList, selFlag);

    k_scanA_V<<<nbV, TPB, 0, stream>>>(selFlag, V, bsumsV);
    k_scanB<<<1, TPB, 0, stream>>>(bsumsV, nbV, nullptr, nullptr);
    k_scanC_V<<<nbV, TPB, 0, stream>>>(selFlag, V, bsumsV, mask, selIdx, vidx, O2);

    k_scanA_E<<<nbE, TPB, 0, stream>>>(edges, E, mask, bsumsE);
    k_scanB<<<1, TPB, 0, stream>>>(bsumsE, nbE, &state[4], O4);
    k_scanC_E<<<nbE, TPB, 0, stream>>>(edges, E, mask, bsumsE, state, eidx, O1, O3);

    k_verts_up<<<(k * 32 + TPB - 1) / TPB, TPB, 0, stream>>>(verts, selIdx, attnf, O0, k);
}

// Round 9
// 379.503 us; speedup vs baseline: 1.1951x; 1.1951x over previous
//
#include <hip/hip_runtime.h>
#include <math.h>

#define TPB 256
#define SCAN_ITEMS 4
#define SCAN_BLOCK (TPB * SCAN_ITEMS)
#define TIECAP 2048
#define HIST_BLOCKS 104
#define BW 512                // bucket width in vertices (2^9)
#define BUCKET_BLOCKS 256     // contiguous chunk per block keeps bucket ranges dense
#define BIG 1024              // big block for latency-bound scatter/gather kernels

// ---------------- block-wide exclusive scan helper (256 threads = 4 waves) ----
static __device__ __forceinline__ int block_scan_excl(int v, int* lds, int& total)
{
    int lane = threadIdx.x & 63;
    int wid  = threadIdx.x >> 6;
    int x = v;
#pragma unroll
    for (int off = 1; off < 64; off <<= 1) {
        int y = __shfl_up(x, off, 64);
        if (lane >= off) x += y;
    }
    if (lane == 63) lds[wid] = x;
    __syncthreads();
    int t0 = lds[0], t1 = lds[1], t2 = lds[2], t3 = lds[3];
    int wOff = (wid > 0 ? t0 : 0) + (wid > 1 ? t1 : 0) + (wid > 2 ? t2 : 0);
    total = t0 + t1 + t2 + t3;
    __syncthreads();
    return wOff + x - v;   // exclusive prefix of this thread's value
}

// ---------------- init: zero hists + state + bucket cursors ----------------
__global__ void k_init(unsigned* hist, unsigned* state, int k,
                       unsigned* cursor, int NB, int CAP)
{
    int i = threadIdx.x;
    for (int j = i; j < 1024; j += blockDim.x) hist[j] = 0u;
    if (cursor) {
        for (int j = i; j < NB; j += blockDim.x)
            cursor[j * 16] = (unsigned)(j * CAP);   // 64B-padded cursors
    }
    if (i == 0) {
        state[0] = 0u;            // prefix
        state[1] = (unsigned)k;   // kk remaining
        state[2] = 0u;            // T
        state[3] = 0u;            // tie count
        state[4] = 0u;            // nValid
    }
}

// ---------------- per-vertex dot products (wave per vertex) ----------------
__global__ void k_dots(const float* __restrict__ verts,
                       const float* __restrict__ w0, const float* __restrict__ b0,
                       const float* __restrict__ w1, const float* __restrict__ b1,
                       long long* __restrict__ iacc, long long* __restrict__ s1q, int V)
{
    int gid  = blockIdx.x * blockDim.x + threadIdx.x;
    int v    = gid >> 6;
    int lane = gid & 63;
    if (v >= V) return;
    const float2 a  = ((const float2*)(verts + (size_t)v * 128))[lane];
    const float2 wa = ((const float2*)w0)[lane];
    const float2 wb = ((const float2*)w1)[lane];
    float p0 = a.x * wa.x + a.y * wa.y;
    float p1 = a.x * wb.x + a.y * wb.y;
#pragma unroll
    for (int off = 32; off > 0; off >>= 1) {
        p0 += __shfl_down(p0, off, 64);
        p1 += __shfl_down(p1, off, 64);
    }
    if (lane == 0) {
        double s0 = (double)p0 + (double)b0[0];
        double s1 = (double)p1 + (double)b1[0];
        iacc[v] = (long long)llrint(s0 * 1099511627776.0);   // 2^40 fixed point
        s1q[v]  = (long long)llrint(s1 * 1099511627776.0);
    }
}

// ---------------- fallback edge scatter (device atomics) -------------------
__global__ void k_scatter(const int2* __restrict__ edges, const long long* __restrict__ s1q,
                          unsigned long long* __restrict__ iacc, int E)
{
    int i = blockIdx.x * blockDim.x + threadIdx.x;
    if (i >= E) return;
    int2 e = edges[i];
    atomicAdd(&iacc[e.x], (unsigned long long)s1q[e.y]);
    atomicAdd(&iacc[e.y], (unsigned long long)s1q[e.x]);
}

// ---------------- phase 1: bucket the 2E endpoint updates ------------------
// 4B element = (src << 9) | (dst & 511); bucket = dst >> 9. Values are NOT
// carried here — k_bucket_sum gathers s1q[src] from L2. Contiguous chunk per
// block keeps each block's per-bucket reserved range dense (write coalescing).
__global__ void __launch_bounds__(BIG)
k_bucket(const int2* __restrict__ edges, unsigned* __restrict__ bdata,
         unsigned* __restrict__ cursor, int E, int NB, int CAP, int chunk)
{
    __shared__ unsigned cnt[256];
    __shared__ unsigned base[256];
    const int tid   = threadIdx.x;
    const int start = blockIdx.x * chunk;
    const int end   = min(E, start + chunk);
    for (int j = tid; j < 256; j += BIG) cnt[j] = 0u;
    __syncthreads();
    // pass A: count this block's elements per bucket
    for (int i = start + tid; i < end; i += BIG) {
        int2 e = edges[i];
        atomicAdd(&cnt[e.x >> 9], 1u);
        atomicAdd(&cnt[e.y >> 9], 1u);
    }
    __syncthreads();
    // reserve contiguous ranges (one global atomic per bucket per block)
    if (tid < NB) {
        unsigned c = cnt[tid];
        base[tid] = c ? atomicAdd(&cursor[tid * 16], c) : 0u;
        cnt[tid] = 0u;   // reuse as local write cursor
    }
    __syncthreads();
    // pass B: re-read edges (L2-hot), write packed 4B elements
    for (int i = start + tid; i < end; i += BIG) {
        int2 e = edges[i];
        int b0 = e.x >> 9;
        unsigned p0 = base[b0] + atomicAdd(&cnt[b0], 1u);
        if (p0 < (unsigned)(b0 + 1) * (unsigned)CAP)
            bdata[p0] = ((unsigned)e.y << 9) | (unsigned)(e.x & 511);
        int b1 = e.y >> 9;
        unsigned p1 = base[b1] + atomicAdd(&cnt[b1], 1u);
        if (p1 < (unsigned)(b1 + 1) * (unsigned)CAP)
            bdata[p1] = ((unsigned)e.x << 9) | (unsigned)(e.y & 511);
    }
}

// ---------------- phase 2: per-bucket sum + finalize + hist round 0 --------
// Block b owns vertices [b*BW, b*BW+BW): gathers s1q[src] (L2-resident),
// accumulates in LDS, emits attnf/keys, and counts radix-hist round 0.
__global__ void __launch_bounds__(BIG)
k_bucket_sum(const unsigned* __restrict__ bdata, const unsigned* __restrict__ cursor,
             const long long* __restrict__ s1q, const long long* __restrict__ iacc,
             float* __restrict__ attnf, unsigned* __restrict__ keys,
             unsigned* __restrict__ hist, int V, int CAP)
{
    __shared__ unsigned long long acc[BW];
    __shared__ unsigned lh[256];
    const int b   = blockIdx.x;
    const int tid = threadIdx.x;
    for (int j = tid; j < BW;  j += BIG) acc[j] = 0ull;
    for (int j = tid; j < 256; j += BIG) lh[j] = 0u;
    __syncthreads();
    unsigned n = cursor[b * 16] - (unsigned)(b * CAP);
    if (n > (unsigned)CAP) n = (unsigned)CAP;
    const unsigned* src = bdata + (size_t)b * CAP;
    for (unsigned i = tid; i < n; i += BIG) {
        unsigned p = src[i];
        atomicAdd(&acc[p & 511u], (unsigned long long)s1q[p >> 9]);
    }
    __syncthreads();
    for (int j = tid; j < BW; j += BIG) {
        int v = b * BW + j;
        if (v < V) {
            long long tot = iacc[v] + (long long)acc[j];
            float a = (float)((double)tot * 9.094947017729282379150390625e-13); // 2^-40
            attnf[v] = a;
            unsigned u = __float_as_uint(a);
            unsigned key = (u & 0x80000000u) ? ~u : (u | 0x80000000u);
            keys[v] = key;
            atomicAdd(&lh[key >> 24], 1u);   // radix round 0 (shift=24)
        }
    }
    __syncthreads();
    for (int j = tid; j < 256; j += BIG) {
        unsigned c = lh[j];
        if (c) atomicAdd(&hist[j], c);
    }
}

// ---------------- fixed point -> float attn + sortable key (fallback) ------
__global__ void k_finalize(const long long* __restrict__ iacc, float* __restrict__ attnf,
                           unsigned* __restrict__ keys, int V)
{
    int i = blockIdx.x * blockDim.x + threadIdx.x;
    if (i >= V) return;
    float a = (float)((double)iacc[i] * 9.094947017729282379150390625e-13); // 2^-40
    attnf[i] = a;
    unsigned u = __float_as_uint(a);
    keys[i] = (u & 0x80000000u) ? ~u : (u | 0x80000000u);
}

// ---------------- radix select: LDS-privatized histogram pass --------------
__global__ void k_hist(const unsigned* __restrict__ keys, int V,
                       const unsigned* __restrict__ state, int shift,
                       unsigned* __restrict__ hist)
{
    __shared__ unsigned lh[256];
    lh[threadIdx.x] = 0u;      // TPB == 256
    __syncthreads();
    unsigned pref = 0u;
    if (shift != 24) pref = state[0] >> (shift + 8);
    int stride = gridDim.x * blockDim.x;
    for (int i = blockIdx.x * blockDim.x + threadIdx.x; i < V; i += stride) {
        unsigned key = keys[i];
        bool ok = (shift == 24) || ((key >> (shift + 8)) == pref);
        if (ok) atomicAdd(&lh[(key >> shift) & 255u], 1u);
    }
    __syncthreads();
    unsigned c = lh[threadIdx.x];
    if (c) atomicAdd(&hist[threadIdx.x], c);
}

// ---------------- radix select: pick bin -----------------------------------
__global__ void k_select(const unsigned* __restrict__ hist, int shift, unsigned* __restrict__ state)
{
    if (threadIdx.x != 0 || blockIdx.x != 0) return;
    unsigned kk = state[1];
    unsigned cum = 0;
    int j = 255;
    for (; j > 0; --j) {
        unsigned c = hist[j];
        if (cum + c >= kk) break;
        cum += c;
    }
    state[0] |= ((unsigned)j) << shift;
    state[1] = kk - cum;
    if (shift == 0) state[2] = state[0];  // final threshold key T
}

// ---------------- fused: mark key>T + collect ties + block totals ----------
__global__ void k_mark(const unsigned* __restrict__ keys, int V,
                       unsigned* __restrict__ state, int* __restrict__ selFlag,
                       int* __restrict__ tieList, unsigned* __restrict__ bsums)
{
    __shared__ int lds[4];
    const unsigned T = state[2];
    int base = blockIdx.x * SCAN_BLOCK + threadIdx.x * SCAN_ITEMS;
    int f[4] = {0, 0, 0, 0};
    unsigned kv[4];
    bool full = (base + 3 < V);
    if (full) {
        uint4 q = *(const uint4*)(keys + base);
        kv[0] = q.x; kv[1] = q.y; kv[2] = q.z; kv[3] = q.w;
    } else {
#pragma unroll
        for (int t = 0; t < 4; ++t)
            kv[t] = (base + t < V) ? keys[base + t] : 0u;
    }
#pragma unroll
    for (int t = 0; t < 4; ++t) {
        if (base + t < V) {
            f[t] = kv[t] > T ? 1 : 0;
            if (kv[t] == T) {
                unsigned p = atomicAdd(&state[3], 1u);
                if (p < TIECAP) tieList[p] = base + t;
            }
        }
    }
    if (full) {
        *(int4*)(selFlag + base) = make_int4(f[0], f[1], f[2], f[3]);
    } else {
#pragma unroll
        for (int t = 0; t < 4; ++t)
            if (base + t < V) selFlag[base + t] = f[t];
    }
    int tot;
    block_scan_excl(f[0] + f[1] + f[2] + f[3], lds, tot);
    if (threadIdx.x == 0) bsums[blockIdx.x] = (unsigned)tot;
}

// ---------------- resolve ties: smallest kk indices among == T --------------
// Also patches bsums (runs BEFORE scanB turns counts into prefixes).
__global__ void k_tie_resolve(const unsigned* __restrict__ state,
                              const int* __restrict__ tieList, int* __restrict__ selFlag,
                              unsigned* __restrict__ bsums)
{
    __shared__ int s[TIECAP];
    int n  = (int)state[3];
    if (n > TIECAP) n = TIECAP;
    int kk = (int)state[1];
    int tid = threadIdx.x;
    if (kk >= n) {
        for (int i = tid; i < n; i += blockDim.x) {
            int v = tieList[i];
            selFlag[v] = 1;
            atomicAdd(&bsums[v / SCAN_BLOCK], 1u);
        }
        return;
    }
    for (int i = tid; i < n; i += blockDim.x) s[i] = tieList[i];
    __syncthreads();
    for (int i = tid; i < n; i += blockDim.x) {
        int v = s[i];
        int r = 0;
        for (int j = 0; j < n; ++j) r += (s[j] < v);
        if (r < kk) {
            selFlag[v] = 1;
            atomicAdd(&bsums[v / SCAN_BLOCK], 1u);
        }
    }
}

// ---------------- scan pass B: single block over block sums -----------------
__global__ void k_scanB(unsigned* __restrict__ sums, int nb,
                        unsigned* __restrict__ totalOut, float* __restrict__ outF)
{
    __shared__ int lds[4];
    int tid = threadIdx.x;
    int running = 0;
    for (int base = 0; base < nb; base += TPB) {
        int i = base + tid;
        int v = (i < nb) ? (int)sums[i] : 0;
        int tot;
        int ex = block_scan_excl(v, lds, tot);
        if (i < nb) sums[i] = (unsigned)(ex + running);
        running += tot;
    }
    if (tid == 0) {
        if (totalOut) *totalOut = (unsigned)running;
        if (outF)     *outF    = (float)running;
    }
}

// ---------------- scan over V: pass C (write mask / selIdx / O2) ------------
__global__ void k_scanC_V(const int* __restrict__ selFlag, int V,
                          const unsigned* __restrict__ bsums,
                          int* __restrict__ mask, int* __restrict__ selIdx,
                          const int* __restrict__ vidx_in, float* __restrict__ O2)
{
    __shared__ int lds[4];
    int base = blockIdx.x * SCAN_BLOCK + threadIdx.x * SCAN_ITEMS;
    int f[4] = {0, 0, 0, 0};
    if (base + 3 < V) {
        int4 q = *(const int4*)(selFlag + base);
        f[0] = q.x; f[1] = q.y; f[2] = q.z; f[3] = q.w;
    } else {
#pragma unroll
        for (int t = 0; t < 4; ++t)
            if (base + t < V) f[t] = selFlag[base + t];
    }
    int tot;
    int run = block_scan_excl(f[0] + f[1] + f[2] + f[3], lds, tot) + (int)bsums[blockIdx.x];
#pragma unroll
    for (int t = 0; t < 4; ++t) {
        int idx = base + t;
        if (idx < V) {
            if (f[t]) {
                mask[idx]    = run;
                selIdx[run]  = idx;
                O2[run]      = (float)vidx_in[run];  // verts_idx[:k]
                run++;
            } else {
                mask[idx] = -1;
            }
        }
    }
}

// ---------------- scan over E: pass A ---------------------------------------
__global__ void k_scanA_E(const int* __restrict__ edges, int E, const int* __restrict__ mask,
                          unsigned* __restrict__ bsums)
{
    __shared__ int lds[4];
    int base = blockIdx.x * SCAN_BLOCK + threadIdx.x * SCAN_ITEMS;
    int s = 0;
    if (base + 3 < E) {
        const int4* e4 = (const int4*)edges;
        int4 q0 = e4[(base >> 1)];
        int4 q1 = e4[(base >> 1) + 1];
        s += (mask[q0.x] >= 0 && mask[q0.y] >= 0);
        s += (mask[q0.z] >= 0 && mask[q0.w] >= 0);
        s += (mask[q1.x] >= 0 && mask[q1.y] >= 0);
        s += (mask[q1.z] >= 0 && mask[q1.w] >= 0);
    } else {
        for (int t = 0; t < 4; ++t) {
            int i = base + t;
            if (i < E) {
                int a = edges[2 * i], b = edges[2 * i + 1];
                s += (mask[a] >= 0 && mask[b] >= 0);
            }
        }
    }
    int tot;
    block_scan_excl(s, lds, tot);
    if (threadIdx.x == 0) bsums[blockIdx.x] = (unsigned)tot;
}

// ---------------- scan over E: pass C (write O1 new_edges, O3 edges_idx) ----
__global__ void k_scanC_E(const int* __restrict__ edges, int E, const int* __restrict__ mask,
                          const unsigned* __restrict__ bsums, const unsigned* __restrict__ state,
                          const int* __restrict__ eidx_in,
                          float* __restrict__ O1, float* __restrict__ O3)
{
    __shared__ int lds[4];
    int base = blockIdx.x * SCAN_BLOCK + threadIdx.x * SCAN_ITEMS;
    int fl[4] = {0, 0, 0, 0};
    int m0s[4], m1s[4];
    int s = 0;
#pragma unroll
    for (int t = 0; t < 4; ++t) {
        int i = base + t;
        if (i < E) {
            int2 e = ((const int2*)edges)[i];
            int m0 = mask[e.x], m1 = mask[e.y];
            m0s[t] = m0; m1s[t] = m1;
            fl[t] = (m0 >= 0 && m1 >= 0);
            s += fl[t];
        }
    }
    int tot;
    int run = block_scan_excl(s, lds, tot) + (int)bsums[blockIdx.x];
    int nValid = (int)state[4];
#pragma unroll
    for (int t = 0; t < 4; ++t) {
        int i = base + t;
        if (i < E) {
            long long pos = fl[t] ? (long long)run : (long long)nValid + (long long)(i - run);
            float2 val;
            if (fl[t]) { val.x = (float)m0s[t]; val.y = (float)m1s[t]; }
            else       { val.x = -1.0f;         val.y = -1.0f; }
            ((float2*)O1)[pos] = val;
            O3[pos] = fl[t] ? (float)eidx_in[i] : -1.0f;
            run += fl[t];
        }
    }
}

// ---------------- gather + tanh scale: verts_up -----------------------------
__global__ void k_verts_up(const float* __restrict__ verts, const int* __restrict__ selIdx,
                           const float* __restrict__ attnf, float* __restrict__ O0, int k)
{
    int idx = blockIdx.x * blockDim.x + threadIdx.x;
    if (idx >= k * 32) return;
    int r = idx >> 5;
    int c = idx & 31;
    int v = selIdx[r];
    float t = tanhf(attnf[v]);
    float4 x = ((const float4*)verts)[(size_t)v * 32 + c];
    x.x *= t; x.y *= t; x.z *= t; x.w *= t;
    ((float4*)O0)[(size_t)r * 32 + c] = x;
}

// ============================ host launcher ================================
extern "C" void kernel_launch(void* const* d_in, const int* in_sizes, int n_in,
                              void* d_out, int out_size, void* d_ws, size_t ws_size,
                              hipStream_t stream)
{
    const float* verts = (const float*)d_in[0];
    const int*   edges = (const int*)d_in[1];
    const int*   vidx  = (const int*)d_in[2];
    const int*   eidx  = (const int*)d_in[3];
    const float* w0w   = (const float*)d_in[4];
    const float* w0b   = (const float*)d_in[5];
    const float* w1w   = (const float*)d_in[6];
    const float* w1b   = (const float*)d_in[7];

    const int V = in_sizes[2];
    const int E = in_sizes[3];
    const int F = in_sizes[0] / V;            // 128
    const int k = (int)((double)V * 0.8);     // matches python int(nv*RATIO)

    // ---- workspace carve-up ----
    char* p = (char*)d_ws;
    auto alloc = [&](size_t bytes) -> char* {
        char* r = p;
        p += (bytes + 255) & ~(size_t)255;
        return r;
    };
    long long* iacc   = (long long*)alloc((size_t)V * 8);
    long long* s1q    = (long long*)alloc((size_t)V * 8);
    float*     attnf  = (float*)alloc((size_t)V * 4);
    unsigned*  keys   = (unsigned*)alloc((size_t)V * 4);
    int*       selFlag= (int*)alloc((size_t)V * 4);
    int*       mask   = (int*)alloc((size_t)V * 4);
    int*       selIdx = (int*)alloc((size_t)k * 4);
    int*       tieList= (int*)alloc((size_t)TIECAP * 4);
    unsigned*  hist   = (unsigned*)alloc(1024 * 4);
    unsigned*  state  = (unsigned*)alloc(64);
    const int nbV = (V + SCAN_BLOCK - 1) / SCAN_BLOCK;
    const int nbE = (E + SCAN_BLOCK - 1) / SCAN_BLOCK;
    unsigned*  bsumsV = (unsigned*)alloc((size_t)nbV * 4);
    unsigned*  bsumsE = (unsigned*)alloc((size_t)nbE * 4);

    // bucket-aggregation scratch (falls back to atomic scatter if ws too small)
    const int NB  = (V + BW - 1) / BW;
    long long avgc = (2LL * E * BW) / (V > 0 ? V : 1);
    const int CAP = (int)(avgc + avgc / 8 + 1024);   // mean + 12.5% + 1024 (~28 sigma)
    unsigned*  cursor = (unsigned*)alloc(256 * 64);              // 64B-padded
    unsigned*  bdata  = (unsigned*)alloc((size_t)NB * CAP * 4);  // 4B packed elems
    const bool useBucket = (NB <= 256) && (V < (1 << 17)) &&
                           ((size_t)(p - (char*)d_ws) <= ws_size);

    // ---- output carve-up (all written as float values) ----
    float* out = (float*)d_out;
    float* O0 = out;                         // verts_up   k*F
    float* O1 = O0 + (size_t)k * F;          // new_edges  E*2
    float* O2 = O1 + (size_t)E * 2;          // verts_idx  k
    float* O3 = O2 + (size_t)k;              // edges_idx  E
    float* O4 = O3 + (size_t)E;              // n_edges    1

    k_init<<<1, TPB, 0, stream>>>(hist, state, k,
                                  useBucket ? cursor : nullptr, NB, CAP);

    k_dots<<<(int)(((size_t)V * 64 + TPB - 1) / TPB), TPB, 0, stream>>>(
        verts, w0w, w0b, w1w, w1b, iacc, s1q, V);

    if (useBucket) {
        const int chunk = (E + BUCKET_BLOCKS - 1) / BUCKET_BLOCKS;
        k_bucket<<<BUCKET_BLOCKS, BIG, 0, stream>>>(
            (const int2*)edges, bdata, cursor, E, NB, CAP, chunk);
        k_bucket_sum<<<NB, BIG, 0, stream>>>(
            bdata, cursor, s1q, iacc, attnf, keys, hist, V, CAP);
    } else {
        k_scatter<<<(E + TPB - 1) / TPB, TPB, 0, stream>>>(
            (const int2*)edges, s1q, (unsigned long long*)iacc, E);
        k_finalize<<<(V + TPB - 1) / TPB, TPB, 0, stream>>>(iacc, attnf, keys, V);
    }

    for (int r = 0; r < 4; ++r) {
        int shift = 24 - 8 * r;
        if (r > 0 || !useBucket)   // round 0 hist fused into k_bucket_sum
            k_hist<<<HIST_BLOCKS, TPB, 0, stream>>>(keys, V, state, shift, hist + 256 * r);
        k_select<<<1, 64, 0, stream>>>(hist + 256 * r, shift, state);
    }

    k_mark<<<nbV, TPB, 0, stream>>>(keys, V, state, selFlag, tieList, bsumsV);
    k_tie_resolve<<<1, TPB, 0, stream>>>(state, tieList, selFlag, bsumsV);

    k_scanB<<<1, TPB, 0, stream>>>(bsumsV, nbV, nullptr, nullptr);
    k_scanC_V<<<nbV, TPB, 0, stream>>>(selFlag, V, bsumsV, mask, selIdx, vidx, O2);

    k_scanA_E<<<nbE, TPB, 0, stream>>>(edges, E, mask, bsumsE);
    k_scanB<<<1, TPB, 0, stream>>>(bsumsE, nbE, &state[4], O4);
    k_scanC_E<<<nbE, TPB, 0, stream>>>(edges, E, mask, bsumsE, state, eidx, O1, O3);

    k_verts_up<<<(k * 32 + TPB - 1) / TPB, TPB, 0, stream>>>(verts, selIdx, attnf, O0, k);
}

// Round 10
// 379.253 us; speedup vs baseline: 1.1959x; 1.0007x over previous
//
#include <hip/hip_runtime.h>
#include <math.h>

#define TPB 256
#define SCAN_ITEMS 4
#define SCAN_BLOCK (TPB * SCAN_ITEMS)
#define TIECAP 2048
#define HIST_BLOCKS 104
#define BW 512                // bucket width in vertices (2^9)
#define BUCKET_BLOCKS 256     // contiguous chunk per block keeps bucket ranges dense
#define BIG 1024              // big block for latency-bound scatter/gather kernels

// ---------------- block-wide exclusive scan helper (256 threads = 4 waves) ----
static __device__ __forceinline__ int block_scan_excl(int v, int* lds, int& total)
{
    int lane = threadIdx.x & 63;
    int wid  = threadIdx.x >> 6;
    int x = v;
#pragma unroll
    for (int off = 1; off < 64; off <<= 1) {
        int y = __shfl_up(x, off, 64);
        if (lane >= off) x += y;
    }
    if (lane == 63) lds[wid] = x;
    __syncthreads();
    int t0 = lds[0], t1 = lds[1], t2 = lds[2], t3 = lds[3];
    int wOff = (wid > 0 ? t0 : 0) + (wid > 1 ? t1 : 0) + (wid > 2 ? t2 : 0);
    total = t0 + t1 + t2 + t3;
    __syncthreads();
    return wOff + x - v;   // exclusive prefix of this thread's value
}

// ---------------- init: zero hists + state + bucket cursors ----------------
__global__ void k_init(unsigned* hist, unsigned* state, int k,
                       unsigned* cursor, int NB, int CAP)
{
    int i = threadIdx.x;
    for (int j = i; j < 1024; j += blockDim.x) hist[j] = 0u;
    if (cursor) {
        for (int j = i; j < NB; j += blockDim.x)
            cursor[j * 16] = (unsigned)(j * CAP);   // 64B-padded cursors
    }
    if (i == 0) {
        state[0] = 0u;            // prefix
        state[1] = (unsigned)k;   // kk remaining
        state[2] = 0u;            // T
        state[3] = 0u;            // tie count
        state[4] = 0u;            // nValid
    }
}

// ---------------- per-vertex dot products (wave per vertex) ----------------
__global__ void k_dots(const float* __restrict__ verts,
                       const float* __restrict__ w0, const float* __restrict__ b0,
                       const float* __restrict__ w1, const float* __restrict__ b1,
                       long long* __restrict__ iacc, long long* __restrict__ s1q, int V)
{
    int gid  = blockIdx.x * blockDim.x + threadIdx.x;
    int v    = gid >> 6;
    int lane = gid & 63;
    if (v >= V) return;
    const float2 a  = ((const float2*)(verts + (size_t)v * 128))[lane];
    const float2 wa = ((const float2*)w0)[lane];
    const float2 wb = ((const float2*)w1)[lane];
    float p0 = a.x * wa.x + a.y * wa.y;
    float p1 = a.x * wb.x + a.y * wb.y;
#pragma unroll
    for (int off = 32; off > 0; off >>= 1) {
        p0 += __shfl_down(p0, off, 64);
        p1 += __shfl_down(p1, off, 64);
    }
    if (lane == 0) {
        double s0 = (double)p0 + (double)b0[0];
        double s1 = (double)p1 + (double)b1[0];
        iacc[v] = (long long)llrint(s0 * 1099511627776.0);   // 2^40 fixed point
        s1q[v]  = (long long)llrint(s1 * 1099511627776.0);
    }
}

// ---------------- fallback edge scatter (device atomics) -------------------
__global__ void k_scatter(const int2* __restrict__ edges, const long long* __restrict__ s1q,
                          unsigned long long* __restrict__ iacc, int E)
{
    int i = blockIdx.x * blockDim.x + threadIdx.x;
    if (i >= E) return;
    int2 e = edges[i];
    atomicAdd(&iacc[e.x], (unsigned long long)s1q[e.y]);
    atomicAdd(&iacc[e.y], (unsigned long long)s1q[e.x]);
}

// ---------------- phase 1: bucket the 2E endpoint updates ------------------
// 4B element = (src << 9) | (dst & 511); bucket = dst >> 9. Values are NOT
// carried here — k_bucket_sum gathers s1q[src] from L2. Contiguous chunk per
// block keeps each block's per-bucket reserved range dense (write coalescing).
__global__ void __launch_bounds__(BIG)
k_bucket(const int2* __restrict__ edges, unsigned* __restrict__ bdata,
         unsigned* __restrict__ cursor, int E, int NB, int CAP, int chunk)
{
    __shared__ unsigned cnt[256];
    __shared__ unsigned base[256];
    const int tid   = threadIdx.x;
    const int start = blockIdx.x * chunk;
    const int end   = min(E, start + chunk);
    for (int j = tid; j < 256; j += BIG) cnt[j] = 0u;
    __syncthreads();
    // pass A: count this block's elements per bucket
    for (int i = start + tid; i < end; i += BIG) {
        int2 e = edges[i];
        atomicAdd(&cnt[e.x >> 9], 1u);
        atomicAdd(&cnt[e.y >> 9], 1u);
    }
    __syncthreads();
    // reserve contiguous ranges (one global atomic per bucket per block)
    if (tid < NB) {
        unsigned c = cnt[tid];
        base[tid] = c ? atomicAdd(&cursor[tid * 16], c) : 0u;
        cnt[tid] = 0u;   // reuse as local write cursor
    }
    __syncthreads();
    // pass B: re-read edges (L2-hot), write packed 4B elements
    for (int i = start + tid; i < end; i += BIG) {
        int2 e = edges[i];
        int b0 = e.x >> 9;
        unsigned p0 = base[b0] + atomicAdd(&cnt[b0], 1u);
        if (p0 < (unsigned)(b0 + 1) * (unsigned)CAP)
            bdata[p0] = ((unsigned)e.y << 9) | (unsigned)(e.x & 511);
        int b1 = e.y >> 9;
        unsigned p1 = base[b1] + atomicAdd(&cnt[b1], 1u);
        if (p1 < (unsigned)(b1 + 1) * (unsigned)CAP)
            bdata[p1] = ((unsigned)e.x << 9) | (unsigned)(e.y & 511);
    }
}

// ---------------- phase 2: per-bucket sum + finalize + hist round 0 --------
// Block b owns vertices [b*BW, b*BW+BW): gathers s1q[src] (L2-resident),
// accumulates in LDS, emits attnf/keys, and counts radix-hist round 0.
__global__ void __launch_bounds__(BIG)
k_bucket_sum(const unsigned* __restrict__ bdata, const unsigned* __restrict__ cursor,
             const long long* __restrict__ s1q, const long long* __restrict__ iacc,
             float* __restrict__ attnf, unsigned* __restrict__ keys,
             unsigned* __restrict__ hist, int V, int CAP)
{
    __shared__ unsigned long long acc[BW];
    __shared__ unsigned lh[256];
    const int b   = blockIdx.x;
    const int tid = threadIdx.x;
    for (int j = tid; j < BW;  j += BIG) acc[j] = 0ull;
    for (int j = tid; j < 256; j += BIG) lh[j] = 0u;
    __syncthreads();
    unsigned n = cursor[b * 16] - (unsigned)(b * CAP);
    if (n > (unsigned)CAP) n = (unsigned)CAP;
    const unsigned* src = bdata + (size_t)b * CAP;
    for (unsigned i = tid; i < n; i += BIG) {
        unsigned p = src[i];
        atomicAdd(&acc[p & 511u], (unsigned long long)s1q[p >> 9]);
    }
    __syncthreads();
    for (int j = tid; j < BW; j += BIG) {
        int v = b * BW + j;
        if (v < V) {
            long long tot = iacc[v] + (long long)acc[j];
            float a = (float)((double)tot * 9.094947017729282379150390625e-13); // 2^-40
            attnf[v] = a;
            unsigned u = __float_as_uint(a);
            unsigned key = (u & 0x80000000u) ? ~u : (u | 0x80000000u);
            keys[v] = key;
            atomicAdd(&lh[key >> 24], 1u);   // radix round 0 (shift=24)
        }
    }
    __syncthreads();
    for (int j = tid; j < 256; j += BIG) {
        unsigned c = lh[j];
        if (c) atomicAdd(&hist[j], c);
    }
}

// ---------------- fixed point -> float attn + sortable key (fallback) ------
__global__ void k_finalize(const long long* __restrict__ iacc, float* __restrict__ attnf,
                           unsigned* __restrict__ keys, int V)
{
    int i = blockIdx.x * blockDim.x + threadIdx.x;
    if (i >= V) return;
    float a = (float)((double)iacc[i] * 9.094947017729282379150390625e-13); // 2^-40
    attnf[i] = a;
    unsigned u = __float_as_uint(a);
    keys[i] = (u & 0x80000000u) ? ~u : (u | 0x80000000u);
}

// ---------------- radix select: LDS-privatized histogram pass --------------
__global__ void k_hist(const unsigned* __restrict__ keys, int V,
                       const unsigned* __restrict__ state, int shift,
                       unsigned* __restrict__ hist)
{
    __shared__ unsigned lh[256];
    lh[threadIdx.x] = 0u;      // TPB == 256
    __syncthreads();
    unsigned pref = 0u;
    if (shift != 24) pref = state[0] >> (shift + 8);
    int stride = gridDim.x * blockDim.x;
    for (int i = blockIdx.x * blockDim.x + threadIdx.x; i < V; i += stride) {
        unsigned key = keys[i];
        bool ok = (shift == 24) || ((key >> (shift + 8)) == pref);
        if (ok) atomicAdd(&lh[(key >> shift) & 255u], 1u);
    }
    __syncthreads();
    unsigned c = lh[threadIdx.x];
    if (c) atomicAdd(&hist[threadIdx.x], c);
}

// ---------------- radix select: pick bin -----------------------------------
__global__ void k_select(const unsigned* __restrict__ hist, int shift, unsigned* __restrict__ state)
{
    if (threadIdx.x != 0 || blockIdx.x != 0) return;
    unsigned kk = state[1];
    unsigned cum = 0;
    int j = 255;
    for (; j > 0; --j) {
        unsigned c = hist[j];
        if (cum + c >= kk) break;
        cum += c;
    }
    state[0] |= ((unsigned)j) << shift;
    state[1] = kk - cum;
    if (shift == 0) state[2] = state[0];  // final threshold key T
}

// ---------------- fused: mark key>T + collect ties + block totals ----------
__global__ void k_mark(const unsigned* __restrict__ keys, int V,
                       unsigned* __restrict__ state, int* __restrict__ selFlag,
                       int* __restrict__ tieList, unsigned* __restrict__ bsums)
{
    __shared__ int lds[4];
    const unsigned T = state[2];
    int base = blockIdx.x * SCAN_BLOCK + threadIdx.x * SCAN_ITEMS;
    int f[4] = {0, 0, 0, 0};
    unsigned kv[4];
    bool full = (base + 3 < V);
    if (full) {
        uint4 q = *(const uint4*)(keys + base);
        kv[0] = q.x; kv[1] = q.y; kv[2] = q.z; kv[3] = q.w;
    } else {
#pragma unroll
        for (int t = 0; t < 4; ++t)
            kv[t] = (base + t < V) ? keys[base + t] : 0u;
    }
#pragma unroll
    for (int t = 0; t < 4; ++t) {
        if (base + t < V) {
            f[t] = kv[t] > T ? 1 : 0;
            if (kv[t] == T) {
                unsigned p = atomicAdd(&state[3], 1u);
                if (p < TIECAP) tieList[p] = base + t;
            }
        }
    }
    if (full) {
        *(int4*)(selFlag + base) = make_int4(f[0], f[1], f[2], f[3]);
    } else {
#pragma unroll
        for (int t = 0; t < 4; ++t)
            if (base + t < V) selFlag[base + t] = f[t];
    }
    int tot;
    block_scan_excl(f[0] + f[1] + f[2] + f[3], lds, tot);
    if (threadIdx.x == 0) bsums[blockIdx.x] = (unsigned)tot;
}

// ---------------- resolve ties: smallest kk indices among == T --------------
// Also patches bsums (runs BEFORE scanB turns counts into prefixes).
__global__ void k_tie_resolve(const unsigned* __restrict__ state,
                              const int* __restrict__ tieList, int* __restrict__ selFlag,
                              unsigned* __restrict__ bsums)
{
    __shared__ int s[TIECAP];
    int n  = (int)state[3];
    if (n > TIECAP) n = TIECAP;
    int kk = (int)state[1];
    int tid = threadIdx.x;
    if (kk >= n) {
        for (int i = tid; i < n; i += blockDim.x) {
            int v = tieList[i];
            selFlag[v] = 1;
            atomicAdd(&bsums[v / SCAN_BLOCK], 1u);
        }
        return;
    }
    for (int i = tid; i < n; i += blockDim.x) s[i] = tieList[i];
    __syncthreads();
    for (int i = tid; i < n; i += blockDim.x) {
        int v = s[i];
        int r = 0;
        for (int j = 0; j < n; ++j) r += (s[j] < v);
        if (r < kk) {
            selFlag[v] = 1;
            atomicAdd(&bsums[v / SCAN_BLOCK], 1u);
        }
    }
}

// ---------------- scan pass B: single block over block sums -----------------
__global__ void k_scanB(unsigned* __restrict__ sums, int nb,
                        unsigned* __restrict__ totalOut, float* __restrict__ outF)
{
    __shared__ int lds[4];
    int tid = threadIdx.x;
    int running = 0;
    for (int base = 0; base < nb; base += TPB) {
        int i = base + tid;
        int v = (i < nb) ? (int)sums[i] : 0;
        int tot;
        int ex = block_scan_excl(v, lds, tot);
        if (i < nb) sums[i] = (unsigned)(ex + running);
        running += tot;
    }
    if (tid == 0) {
        if (totalOut) *totalOut = (unsigned)running;
        if (outF)     *outF    = (float)running;
    }
}

// ---------------- scan over V: pass C (write mask / selIdx / O2) ------------
__global__ void k_scanC_V(const int* __restrict__ selFlag, int V,
                          const unsigned* __restrict__ bsums,
                          int* __restrict__ mask, int* __restrict__ selIdx,
                          const int* __restrict__ vidx_in, float* __restrict__ O2)
{
    __shared__ int lds[4];
    int base = blockIdx.x * SCAN_BLOCK + threadIdx.x * SCAN_ITEMS;
    int f[4] = {0, 0, 0, 0};
    if (base + 3 < V) {
        int4 q = *(const int4*)(selFlag + base);
        f[0] = q.x; f[1] = q.y; f[2] = q.z; f[3] = q.w;
    } else {
#pragma unroll
        for (int t = 0; t < 4; ++t)
            if (base + t < V) f[t] = selFlag[base + t];
    }
    int tot;
    int run = block_scan_excl(f[0] + f[1] + f[2] + f[3], lds, tot) + (int)bsums[blockIdx.x];
#pragma unroll
    for (int t = 0; t < 4; ++t) {
        int idx = base + t;
        if (idx < V) {
            if (f[t]) {
                mask[idx]    = run;
                selIdx[run]  = idx;
                O2[run]      = (float)vidx_in[run];  // verts_idx[:k]
                run++;
            } else {
                mask[idx] = -1;
            }
        }
    }
}

// ---------------- scan over E: pass A ---------------------------------------
__global__ void k_scanA_E(const int* __restrict__ edges, int E, const int* __restrict__ mask,
                          unsigned* __restrict__ bsums)
{
    __shared__ int lds[4];
    int base = blockIdx.x * SCAN_BLOCK + threadIdx.x * SCAN_ITEMS;
    int s = 0;
    if (base + 3 < E) {
        const int4* e4 = (const int4*)edges;
        int4 q0 = e4[(base >> 1)];
        int4 q1 = e4[(base >> 1) + 1];
        s += (mask[q0.x] >= 0 && mask[q0.y] >= 0);
        s += (mask[q0.z] >= 0 && mask[q0.w] >= 0);
        s += (mask[q1.x] >= 0 && mask[q1.y] >= 0);
        s += (mask[q1.z] >= 0 && mask[q1.w] >= 0);
    } else {
        for (int t = 0; t < 4; ++t) {
            int i = base + t;
            if (i < E) {
                int a = edges[2 * i], b = edges[2 * i + 1];
                s += (mask[a] >= 0 && mask[b] >= 0);
            }
        }
    }
    int tot;
    block_scan_excl(s, lds, tot);
    if (threadIdx.x == 0) bsums[blockIdx.x] = (unsigned)tot;
}

// ---------------- scan over E: pass C — LDS-compacted dense writes ----------
// Valid outputs of this block form ONE contiguous range [vstart, vstart+tot);
// invalid outputs form one contiguous range in the tail with CONSTANT payload.
// Compact valid tuples in LDS, then write both ranges fully coalesced
// (kills the partial-line write-allocate amplification seen in round 9).
__global__ void k_scanC_E(const int* __restrict__ edges, int E, const int* __restrict__ mask,
                          const unsigned* __restrict__ bsums, const unsigned* __restrict__ state,
                          const int* __restrict__ eidx_in,
                          float* __restrict__ O1, float* __restrict__ O3)
{
    __shared__ int lds[4];
    __shared__ float2 lv[SCAN_BLOCK];   // compacted (m0,m1) pairs
    __shared__ float  le[SCAN_BLOCK];   // compacted eidx values
    const int start = blockIdx.x * SCAN_BLOCK;
    const int base  = start + threadIdx.x * SCAN_ITEMS;
    int fl[4] = {0, 0, 0, 0};
    float2 mv[4];
    float  ev[4];
    int s = 0;
#pragma unroll
    for (int t = 0; t < 4; ++t) {
        int i = base + t;
        if (i < E) {
            int2 e = ((const int2*)edges)[i];
            int m0 = mask[e.x], m1 = mask[e.y];
            fl[t] = (m0 >= 0 && m1 >= 0);
            if (fl[t]) {
                mv[t] = make_float2((float)m0, (float)m1);
                ev[t] = (float)eidx_in[i];
            }
            s += fl[t];
        }
    }
    int tot;
    int lrun = block_scan_excl(s, lds, tot);
#pragma unroll
    for (int t = 0; t < 4; ++t) {
        int i = base + t;
        if (i < E && fl[t]) {
            lv[lrun] = mv[t];
            le[lrun] = ev[t];
            lrun++;
        }
    }
    __syncthreads();
    const int items = min(E - start, SCAN_BLOCK);
    const unsigned vstart = bsums[blockIdx.x];
    const unsigned istart = state[4] + (unsigned)start - vstart;   // nValid + invalid prefix
    for (int j = threadIdx.x; j < tot; j += TPB) {
        ((float2*)O1)[vstart + j] = lv[j];
        O3[vstart + j] = le[j];
    }
    const int ninv = items - tot;
    for (int j = threadIdx.x; j < ninv; j += TPB) {
        ((float2*)O1)[istart + j] = make_float2(-1.0f, -1.0f);
        O3[istart + j] = -1.0f;
    }
}

// ---------------- gather + tanh scale: verts_up -----------------------------
__global__ void k_verts_up(const float* __restrict__ verts, const int* __restrict__ selIdx,
                           const float* __restrict__ attnf, float* __restrict__ O0, int k)
{
    int idx = blockIdx.x * blockDim.x + threadIdx.x;
    if (idx >= k * 32) return;
    int r = idx >> 5;
    int c = idx & 31;
    int v = selIdx[r];
    float t = tanhf(attnf[v]);
    float4 x = ((const float4*)verts)[(size_t)v * 32 + c];
    x.x *= t; x.y *= t; x.z *= t; x.w *= t;
    ((float4*)O0)[(size_t)r * 32 + c] = x;
}

// ============================ host launcher ================================
extern "C" void kernel_launch(void* const* d_in, const int* in_sizes, int n_in,
                              void* d_out, int out_size, void* d_ws, size_t ws_size,
                              hipStream_t stream)
{
    const float* verts = (const float*)d_in[0];
    const int*   edges = (const int*)d_in[1];
    const int*   vidx  = (const int*)d_in[2];
    const int*   eidx  = (const int*)d_in[3];
    const float* w0w   = (const float*)d_in[4];
    const float* w0b   = (const float*)d_in[5];
    const float* w1w   = (const float*)d_in[6];
    const float* w1b   = (const float*)d_in[7];

    const int V = in_sizes[2];
    const int E = in_sizes[3];
    const int F = in_sizes[0] / V;            // 128
    const int k = (int)((double)V * 0.8);     // matches python int(nv*RATIO)

    // ---- workspace carve-up ----
    char* p = (char*)d_ws;
    auto alloc = [&](size_t bytes) -> char* {
        char* r = p;
        p += (bytes + 255) & ~(size_t)255;
        return r;
    };
    long long* iacc   = (long long*)alloc((size_t)V * 8);
    long long* s1q    = (long long*)alloc((size_t)V * 8);
    float*     attnf  = (float*)alloc((size_t)V * 4);
    unsigned*  keys   = (unsigned*)alloc((size_t)V * 4);
    int*       selFlag= (int*)alloc((size_t)V * 4);
    int*       mask   = (int*)alloc((size_t)V * 4);
    int*       selIdx = (int*)alloc((size_t)k * 4);
    int*       tieList= (int*)alloc((size_t)TIECAP * 4);
    unsigned*  hist   = (unsigned*)alloc(1024 * 4);
    unsigned*  state  = (unsigned*)alloc(64);
    const int nbV = (V + SCAN_BLOCK - 1) / SCAN_BLOCK;
    const int nbE = (E + SCAN_BLOCK - 1) / SCAN_BLOCK;
    unsigned*  bsumsV = (unsigned*)alloc((size_t)nbV * 4);
    unsigned*  bsumsE = (unsigned*)alloc((size_t)nbE * 4);

    // bucket-aggregation scratch (falls back to atomic scatter if ws too small)
    const int NB  = (V + BW - 1) / BW;
    long long avgc = (2LL * E * BW) / (V > 0 ? V : 1);
    const int CAP = (int)(avgc + avgc / 8 + 1024);   // mean + 12.5% + 1024 (~28 sigma)
    unsigned*  cursor = (unsigned*)alloc(256 * 64);              // 64B-padded
    unsigned*  bdata  = (unsigned*)alloc((size_t)NB * CAP * 4);  // 4B packed elems
    const bool useBucket = (NB <= 256) && (V < (1 << 17)) &&
                           ((size_t)(p - (char*)d_ws) <= ws_size);

    // ---- output carve-up (all written as float values) ----
    float* out = (float*)d_out;
    float* O0 = out;                         // verts_up   k*F
    float* O1 = O0 + (size_t)k * F;          // new_edges  E*2
    float* O2 = O1 + (size_t)E * 2;          // verts_idx  k
    float* O3 = O2 + (size_t)k;              // edges_idx  E
    float* O4 = O3 + (size_t)E;              // n_edges    1

    k_init<<<1, TPB, 0, stream>>>(hist, state, k,
                                  useBucket ? cursor : nullptr, NB, CAP);

    k_dots<<<(int)(((size_t)V * 64 + TPB - 1) / TPB), TPB, 0, stream>>>(
        verts, w0w, w0b, w1w, w1b, iacc, s1q, V);

    if (useBucket) {
        const int chunk = (E + BUCKET_BLOCKS - 1) / BUCKET_BLOCKS;
        k_bucket<<<BUCKET_BLOCKS, BIG, 0, stream>>>(
            (const int2*)edges, bdata, cursor, E, NB, CAP, chunk);
        k_bucket_sum<<<NB, BIG, 0, stream>>>(
            bdata, cursor, s1q, iacc, attnf, keys, hist, V, CAP);
    } else {
        k_scatter<<<(E + TPB - 1) / TPB, TPB, 0, stream>>>(
            (const int2*)edges, s1q, (unsigned long long*)iacc, E);
        k_finalize<<<(V + TPB - 1) / TPB, TPB, 0, stream>>>(iacc, attnf, keys, V);
    }

    for (int r = 0; r < 4; ++r) {
        int shift = 24 - 8 * r;
        if (r > 0 || !useBucket)   // round 0 hist fused into k_bucket_sum
            k_hist<<<HIST_BLOCKS, TPB, 0, stream>>>(keys, V, state, shift, hist + 256 * r);
        k_select<<<1, 64, 0, stream>>>(hist + 256 * r, shift, state);
    }

    k_mark<<<nbV, TPB, 0, stream>>>(keys, V, state, selFlag, tieList, bsumsV);
    k_tie_resolve<<<1, TPB, 0, stream>>>(state, tieList, selFlag, bsumsV);

    k_scanB<<<1, TPB, 0, stream>>>(bsumsV, nbV, nullptr, nullptr);
    k_scanC_V<<<nbV, TPB, 0, stream>>>(selFlag, V, bsumsV, mask, selIdx, vidx, O2);

    k_scanA_E<<<nbE, TPB, 0, stream>>>(edges, E, mask, bsumsE);
    k_scanB<<<1, TPB, 0, stream>>>(bsumsE, nbE, &state[4], O4);
    k_scanC_E<<<nbE, TPB, 0, stream>>>(edges, E, mask, bsumsE, state, eidx, O1, O3);

    k_verts_up<<<(k * 32 + TPB - 1) / TPB, TPB, 0, stream>>>(verts, selIdx, attnf, O0, k);
}